// Round 10
// baseline (137.543 us; speedup 1.0000x reference)
//
#include <hip/hip_runtime.h>
#include <math.h>

typedef unsigned short u16;
typedef __attribute__((ext_vector_type(8))) short short8;
typedef __attribute__((ext_vector_type(8))) unsigned short ushort8;
typedef __attribute__((ext_vector_type(4))) float floatx4;
typedef __attribute__((ext_vector_type(2))) unsigned int uint2v;

#define SEQ 1024
#define CDIM 384
#define NH 8
#define DH 48
#define DP 64   // padded head dim for Q/K storage
#define NB 8

__device__ __forceinline__ u16 f2bf(float f){
  unsigned int u; __builtin_memcpy(&u, &f, 4);
  u = (u + 0x7fffu + ((u >> 16) & 1u)) >> 16;
  return (u16)u;
}
// pack two fp32 -> two bf16 (RTNE) in one u32: low16 = a, high16 = b
__device__ __forceinline__ unsigned packbf(float a, float b){
  unsigned ua, ub; __builtin_memcpy(&ua, &a, 4); __builtin_memcpy(&ub, &b, 4);
  ua += 0x7fffu + ((ua >> 16) & 1u);
  ub += 0x7fffu + ((ub >> 16) & 1u);
  return __builtin_amdgcn_perm(ub, ua, 0x07060302);
}
__device__ __forceinline__ void async16(const u16* g, u16* l){
  __builtin_amdgcn_global_load_lds((const __attribute__((address_space(1))) void*)g,
                                   (__attribute__((address_space(3))) void*)l, 16, 0, 0);
}

// ---------------- Kernel 1: fused prep ----------------
__global__ __launch_bounds__(256) void prep_kernel(const float* __restrict__ x,
                                                   const float* __restrict__ wq,
                                                   const float* __restrict__ wp,
                                                   u16* __restrict__ xT,
                                                   u16* __restrict__ wdst){
  __shared__ u16 ldsT[64 * 72];
  const int id = blockIdx.x;
  const int t = threadIdx.x;
  if (id < 768){
    const int bx = id & 15, by = (id >> 4) % 6, bz = id / 96;
    const int c0 = by * 64;
    const int s0 = bx * 64;
    const int rr = t >> 2, q4 = t & 3;

    const float* src = x + ((size_t)(bz * CDIM + c0 + rr)) * SEQ + s0;
#pragma unroll
    for (int i = 0; i < 4; i++){
      const int cc = q4 + i * 4;
      float4 f = *(const float4*)(src + cc * 4);
      ldsT[(cc * 4 + 0) * 72 + rr] = f2bf(f.x);
      ldsT[(cc * 4 + 1) * 72 + rr] = f2bf(f.y);
      ldsT[(cc * 4 + 2) * 72 + rr] = f2bf(f.z);
      ldsT[(cc * 4 + 3) * 72 + rr] = f2bf(f.w);
    }
    __syncthreads();
    u16* dst = xT + ((size_t)(bz * SEQ + s0 + rr)) * CDIM + c0 + q4 * 16;
    *(ushort8*)(dst)     = *(const ushort8*)&ldsT[rr * 72 + q4 * 16];
    *(ushort8*)(dst + 8) = *(const ushort8*)&ldsT[rr * 72 + q4 * 16 + 8];
  } else {
    const int NWQ = 3 * CDIM * CDIM;
    const int i = ((id - 768) * 256 + t) * 4;
    const float* src = (i < NWQ) ? (wq + i) : (wp + (i - NWQ));
    float4 f = *(const float4*)src;
    uint2v v; v[0] = packbf(f.x, f.y); v[1] = packbf(f.z, f.w);
    *(uint2v*)(wdst + i) = v;
  }
}

// ---------------- Kernel 2: QKV GEMM (128x128 tile, BK=64, async swizzled staging) ----------------
__global__ __launch_bounds__(256) void qkv_kernel(const u16* __restrict__ W,
                                                  const u16* __restrict__ xT,
                                                  u16* __restrict__ qws,
                                                  u16* __restrict__ kws,
                                                  u16* __restrict__ vws){
  __shared__ u16 ldsA[128 * 64];
  __shared__ u16 ldsB[128 * 64];
  const int t = threadIdx.x;
  const int w = t >> 6, l = t & 63;
  const int quad = l >> 4, li = l & 15;
  const int wm = w >> 1, wn = w & 1;
  const int n0 = blockIdx.x * 128;
  const int m0 = blockIdx.y * 128;
  const int b  = blockIdx.z;

  floatx4 acc[4][4];
#pragma unroll
  for (int i = 0; i < 4; i++)
#pragma unroll
    for (int j = 0; j < 4; j++) acc[i][j] = (floatx4)0.0f;

  const u16* xb = xT + (size_t)b * SEQ * CDIM;
  const int swz = li & 7;

  for (int kk = 0; kk < CDIM; kk += 64){
    __syncthreads();
#pragma unroll
    for (int rep = 0; rep < 4; rep++){
      const int cs = rep * 256 + t;
      const int row = cs >> 3, c4 = cs & 7;
      const int gcol = ((c4 ^ (row & 7)) << 3);
      async16(&W [(size_t)(m0 + row) * CDIM + kk + gcol], &ldsA[cs * 8]);
      async16(&xb[(size_t)(n0 + row) * CDIM + kk + gcol], &ldsB[cs * 8]);
    }
    __syncthreads();
#pragma unroll
    for (int kc = 0; kc < 2; kc++){
      const int rc = ((kc * 4 + quad) ^ swz) << 3;
      short8 af[4], bf[4];
#pragma unroll
      for (int i = 0; i < 4; i++)
        af[i] = *(const short8*)&ldsA[(wm * 64 + i * 16 + li) * 64 + rc];
#pragma unroll
      for (int j = 0; j < 4; j++)
        bf[j] = *(const short8*)&ldsB[(wn * 64 + j * 16 + li) * 64 + rc];
#pragma unroll
      for (int i = 0; i < 4; i++)
#pragma unroll
        for (int j = 0; j < 4; j++)
          acc[i][j] = __builtin_amdgcn_mfma_f32_16x16x32_bf16(af[i], bf[j], acc[i][j], 0, 0, 0);
    }
  }

  const float qs = 0.14433756729740643f * 1.4426950408889634f; // d^-0.5 * log2(e)
  const uint2v z2 = (uint2v)0u;
#pragma unroll
  for (int i = 0; i < 4; i++){
    const int obase = m0 + wm * 64 + i * 16 + quad * 4;
    const int which = obase / CDIM;
    const int rem = obase - which * CDIM;
    const int h = rem / DH;
    const int dd = rem - h * DH;
    const int pair = b * NH + h;
#pragma unroll
    for (int j = 0; j < 4; j++){
      const int s = n0 + wn * 64 + j * 16 + li;
      floatx4 v = acc[i][j];
      if (which == 0){
        uint2v pk; pk[0] = packbf(v[0] * qs, v[1] * qs); pk[1] = packbf(v[2] * qs, v[3] * qs);
        *(uint2v*)&qws[((size_t)pair * SEQ + s) * DP + dd] = pk;
        if ((dd & 48) == 32)
          *(uint2v*)&qws[((size_t)pair * SEQ + s) * DP + dd + 16] = z2;
      } else if (which == 1){
        uint2v pk; pk[0] = packbf(v[0], v[1]); pk[1] = packbf(v[2], v[3]);
        *(uint2v*)&kws[((size_t)pair * SEQ + s) * DP + dd] = pk;
        if ((dd & 48) == 32)
          *(uint2v*)&kws[((size_t)pair * SEQ + s) * DP + dd + 16] = z2;
      } else {
#pragma unroll
        for (int r = 0; r < 4; r++)
          vws[((size_t)pair * DH + dd + r) * SEQ + s] = f2bf(v[r]);
      }
    }
  }
}

// ---------------- Kernel 3: flash attention, pipelined, XCD-swizzled grid ----------------
// 1-D grid of 512: pair = id & 63, qb = id >> 6  =>  id % 8 == pair % 8
// => all 8 q-blocks of a pair land on the same XCD and share its L2 for K/V.
__global__ __launch_bounds__(256) void attn_kernel(const u16* __restrict__ qws,
                                                   const u16* __restrict__ kws,
                                                   const u16* __restrict__ vws,
                                                   u16* __restrict__ aT){
  __shared__ u16 ldsK[2][64 * 64];
  __shared__ u16 ldsV[2][48 * 64];
  __shared__ u16 ldsP[128 * 72];

  const int t = threadIdx.x;
  const int w = t >> 6, l = t & 63;
  const int quad = l >> 4, li = l & 15;
  const int id = blockIdx.x;
  const int pair = id & 63;
  const int qb = id >> 6;
  const int b = pair >> 3, h = pair & 7;
  const int qbase = qb * 128 + w * 32;
  const int swz = li & 7;

  short8 qf[2][2];
#pragma unroll
  for (int mt = 0; mt < 2; mt++){
    const u16* qrow = qws + ((size_t)pair * SEQ + qbase + mt * 16 + li) * DP;
    qf[mt][0] = *(const short8*)(qrow + quad * 8);
    qf[mt][1] = *(const short8*)(qrow + 32 + quad * 8);
  }

  floatx4 ot[3][2];
#pragma unroll
  for (int dt = 0; dt < 3; dt++)
#pragma unroll
    for (int mt = 0; mt < 2; mt++) ot[dt][mt] = (floatx4)0.0f;
  float m_run[2] = {-3.0e38f, -3.0e38f};
  float l_run[2] = {0.0f, 0.0f};

  const u16* kbase = kws + (size_t)pair * SEQ * DP;
  const u16* vbase = vws + (size_t)pair * DH * SEQ;

  auto stage = [&](int kv, int pp){
#pragma unroll
    for (int rep = 0; rep < 4; rep++){
      const int cs = rep * 256 + t;
      if (cs < 512){
        const int row = cs >> 3, c4 = cs & 7;
        async16(&kbase[(size_t)(kv + row) * DP + ((c4 ^ (row & 7)) << 3)],
                &ldsK[pp][cs * 8]);
      } else if (cs < 896){
        const int cs2 = cs - 512;
        const int row = cs2 >> 3, c4 = cs2 & 7;
        async16(&vbase[(size_t)row * SEQ + kv + ((c4 ^ (row & 7)) << 3)],
                &ldsV[pp][cs2 * 8]);
      }
    }
  };

  stage(0, 0);
  for (int i = 0; i < 16; i++){
    const int p = i & 1;
    __syncthreads();                 // drains stage(i) (overlapped with tile i-1 compute)
    if (i < 15) stage((i + 1) * 64, p ^ 1);   // drains at NEXT loop-top barrier

    // ---- S^T[y][m] = K[y][:] . Q[m][:] ----
    floatx4 st[4][2];
#pragma unroll
    for (int yt = 0; yt < 4; yt++){
      const u16* krow = ldsK[p] + (yt * 16 + li) * 64;
      const short8 kf0 = *(const short8*)(krow + (((0 + quad) ^ swz) << 3));
      const short8 kf1 = *(const short8*)(krow + (((4 + quad) ^ swz) << 3));
#pragma unroll
      for (int mt = 0; mt < 2; mt++){
        floatx4 z = (floatx4)0.0f;
        z = __builtin_amdgcn_mfma_f32_16x16x32_bf16(kf0, qf[mt][0], z, 0, 0, 0);
        z = __builtin_amdgcn_mfma_f32_16x16x32_bf16(kf1, qf[mt][1], z, 0, 0, 0);
        st[yt][mt] = z;
      }
    }

    // ---- online softmax; P is wave-private (rows w*32..w*32+31) ----
#pragma unroll
    for (int mt = 0; mt < 2; mt++){
      float mx = -3.0e38f;
#pragma unroll
      for (int yt = 0; yt < 4; yt++)
#pragma unroll
        for (int r = 0; r < 4; r++) mx = fmaxf(mx, st[yt][mt][r]);
      mx = fmaxf(mx, __shfl_xor(mx, 16, 64));
      mx = fmaxf(mx, __shfl_xor(mx, 32, 64));
      const float mnew = fmaxf(m_run[mt], mx);
      const float alpha = __builtin_amdgcn_exp2f(m_run[mt] - mnew);
      m_run[mt] = mnew;

      u16* prow = ldsP + (w * 32 + mt * 16 + li) * 72;
      float ls = 0.0f;
#pragma unroll
      for (int yt = 0; yt < 4; yt++){
        float p0 = __builtin_amdgcn_exp2f(st[yt][mt][0] - mnew);
        float p1 = __builtin_amdgcn_exp2f(st[yt][mt][1] - mnew);
        float p2 = __builtin_amdgcn_exp2f(st[yt][mt][2] - mnew);
        float p3 = __builtin_amdgcn_exp2f(st[yt][mt][3] - mnew);
        ls += (p0 + p1) + (p2 + p3);
        uint2v pk; pk[0] = packbf(p0, p1); pk[1] = packbf(p2, p3);
        *(uint2v*)&prow[yt * 16 + quad * 4] = pk;
      }
      l_run[mt] = l_run[mt] * alpha + ls;
#pragma unroll
      for (int dt = 0; dt < 3; dt++) ot[dt][mt] *= alpha;
    }
    // no barrier: each wave reads only its own P rows (lgkmcnt orders write->read)

    // ---- O^T[d][m] += Vt[d][y] . P[y][m] ----
#pragma unroll
    for (int ks = 0; ks < 64; ks += 32){
      short8 pb[2];
#pragma unroll
      for (int mt = 0; mt < 2; mt++)
        pb[mt] = *(const short8*)&ldsP[(w * 32 + mt * 16 + li) * 72 + ks + quad * 8];
#pragma unroll
      for (int dt = 0; dt < 3; dt++){
        const short8 vf = *(const short8*)&ldsV[p][(dt * 16 + li) * 64 +
                                                  ((((ks >> 3) + quad) ^ swz) << 3)];
#pragma unroll
        for (int mt = 0; mt < 2; mt++)
          ot[dt][mt] = __builtin_amdgcn_mfma_f32_16x16x32_bf16(vf, pb[mt], ot[dt][mt], 0, 0, 0);
      }
    }
  }

  // cross-quad l reduction and write-out
#pragma unroll
  for (int mt = 0; mt < 2; mt++){
    float ls = l_run[mt];
    ls += __shfl_xor(ls, 16, 64);
    ls += __shfl_xor(ls, 32, 64);
    const float rl = __builtin_amdgcn_rcpf(ls);
    const int q = qbase + mt * 16 + li;
#pragma unroll
    for (int dt = 0; dt < 3; dt++){
      floatx4 v = ot[dt][mt];
      uint2v pk; pk[0] = packbf(v[0] * rl, v[1] * rl); pk[1] = packbf(v[2] * rl, v[3] * rl);
      *(uint2v*)&aT[((size_t)b * SEQ + q) * CDIM + h * DH + dt * 16 + quad * 4] = pk;
    }
  }
}

// ---------------- Kernel 4: proj GEMM (128x128 tile, BK=64, async), fp32 out + bias ----------------
__global__ __launch_bounds__(256) void proj_kernel(const u16* __restrict__ W,
                                                   const u16* __restrict__ aT,
                                                   const float* __restrict__ bias,
                                                   float* __restrict__ out){
  __shared__ u16 ldsA[128 * 64];
  __shared__ u16 ldsB[128 * 64];
  const int t = threadIdx.x;
  const int w = t >> 6, l = t & 63;
  const int quad = l >> 4, li = l & 15;
  const int wm = w >> 1, wn = w & 1;
  const int n0 = blockIdx.x * 128;
  const int m0 = blockIdx.y * 128;
  const int b  = blockIdx.z;

  floatx4 acc[4][4];
#pragma unroll
  for (int i = 0; i < 4; i++)
#pragma unroll
    for (int j = 0; j < 4; j++) acc[i][j] = (floatx4)0.0f;

  const u16* ab = aT + (size_t)b * SEQ * CDIM;
  const int swz = li & 7;

  for (int kk = 0; kk < CDIM; kk += 64){
    __syncthreads();
#pragma unroll
    for (int rep = 0; rep < 4; rep++){
      const int cs = rep * 256 + t;
      const int row = cs >> 3, c4 = cs & 7;
      const int gcol = ((c4 ^ (row & 7)) << 3);
      async16(&W [(size_t)(m0 + row) * CDIM + kk + gcol], &ldsA[cs * 8]);
      async16(&ab[(size_t)(n0 + row) * CDIM + kk + gcol], &ldsB[cs * 8]);
    }
    __syncthreads();
#pragma unroll
    for (int kc = 0; kc < 2; kc++){
      const int rc = ((kc * 4 + quad) ^ swz) << 3;
      short8 af[4], bf[4];
#pragma unroll
      for (int i = 0; i < 4; i++)
        af[i] = *(const short8*)&ldsA[(wm * 64 + i * 16 + li) * 64 + rc];
#pragma unroll
      for (int j = 0; j < 4; j++)
        bf[j] = *(const short8*)&ldsB[(wn * 64 + j * 16 + li) * 64 + rc];
#pragma unroll
      for (int i = 0; i < 4; i++)
#pragma unroll
        for (int j = 0; j < 4; j++)
          acc[i][j] = __builtin_amdgcn_mfma_f32_16x16x32_bf16(af[i], bf[j], acc[i][j], 0, 0, 0);
    }
  }

#pragma unroll
  for (int i = 0; i < 4; i++){
    const int o0 = m0 + wm * 64 + i * 16 + quad * 4;
    float bs[4];
#pragma unroll
    for (int r = 0; r < 4; r++) bs[r] = bias[o0 + r];
#pragma unroll
    for (int j = 0; j < 4; j++){
      const int s = n0 + wn * 64 + j * 16 + li;
#pragma unroll
      for (int r = 0; r < 4; r++)
        out[((size_t)b * CDIM + o0 + r) * SEQ + s] = acc[i][j][r] + bs[r];
    }
  }
}

extern "C" void kernel_launch(void* const* d_in, const int* in_sizes, int n_in,
                              void* d_out, int out_size, void* d_ws, size_t ws_size,
                              hipStream_t stream) {
  const float* x      = (const float*)d_in[0];
  const float* w_qkv  = (const float*)d_in[1];
  const float* w_proj = (const float*)d_in[2];
  const float* b_proj = (const float*)d_in[3];
  float* out = (float*)d_out;

  char* ws = (char*)d_ws;
  const size_t SZX = (size_t)NB * SEQ * CDIM * sizeof(u16);       // 6 MB (xT / aT)
  const size_t SZQ = (size_t)NB * NH * SEQ * DP * sizeof(u16);    // 8 MB (padded Q/K)
  const size_t SZV = (size_t)NB * NH * SEQ * DH * sizeof(u16);    // 6 MB
  u16* xT   = (u16*)(ws);
  u16* qws  = (u16*)(ws + SZX);
  u16* kws  = (u16*)(ws + SZX + SZQ);
  u16* vws  = (u16*)(ws + SZX + 2 * SZQ);
  u16* wq_b = (u16*)(ws + SZX + 2 * SZQ + SZV);
  u16* wp_b = wq_b + (size_t)3 * CDIM * CDIM;
  u16* aT   = xT;

  prep_kernel<<<dim3(768 + 576), 256, 0, stream>>>(x, w_qkv, w_proj, xT, wq_b);
  qkv_kernel<<<dim3(8, 9, 8), 256, 0, stream>>>(wq_b, xT, qws, kws, vws);
  attn_kernel<<<dim3(512), 256, 0, stream>>>(qws, kws, vws, aT);
  proj_kernel<<<dim3(8, 3, 8), 256, 0, stream>>>(wp_b, aT, b_proj, out);
}

// Round 11
// 135.190 us; speedup vs baseline: 1.0174x; 1.0174x over previous
//
#include <hip/hip_runtime.h>
#include <math.h>

typedef unsigned short u16;
typedef __attribute__((ext_vector_type(8))) short short8;
typedef __attribute__((ext_vector_type(8))) unsigned short ushort8;
typedef __attribute__((ext_vector_type(4))) float floatx4;
typedef __attribute__((ext_vector_type(2))) unsigned int uint2v;

#define SEQ 1024
#define CDIM 384
#define NH 8
#define DH 48
#define DP 64   // padded head dim for Q/K storage
#define NB 8

__device__ __forceinline__ u16 f2bf(float f){
  unsigned int u; __builtin_memcpy(&u, &f, 4);
  u = (u + 0x7fffu + ((u >> 16) & 1u)) >> 16;
  return (u16)u;
}
// pack two fp32 -> two bf16 (RTNE) in one u32: low16 = a, high16 = b
__device__ __forceinline__ unsigned packbf(float a, float b){
  unsigned ua, ub; __builtin_memcpy(&ua, &a, 4); __builtin_memcpy(&ub, &b, 4);
  ua += 0x7fffu + ((ua >> 16) & 1u);
  ub += 0x7fffu + ((ub >> 16) & 1u);
  return __builtin_amdgcn_perm(ub, ua, 0x07060302);
}
__device__ __forceinline__ void async16(const u16* g, u16* l){
  __builtin_amdgcn_global_load_lds((const __attribute__((address_space(1))) void*)g,
                                   (__attribute__((address_space(3))) void*)l, 16, 0, 0);
}

// ---------------- Kernel 1: fused prep ----------------
__global__ __launch_bounds__(256) void prep_kernel(const float* __restrict__ x,
                                                   const float* __restrict__ wq,
                                                   const float* __restrict__ wp,
                                                   u16* __restrict__ xT,
                                                   u16* __restrict__ wdst){
  __shared__ u16 ldsT[64 * 72];
  const int id = blockIdx.x;
  const int t = threadIdx.x;
  if (id < 768){
    const int bx = id & 15, by = (id >> 4) % 6, bz = id / 96;
    const int c0 = by * 64;
    const int s0 = bx * 64;
    const int rr = t >> 2, q4 = t & 3;

    const float* src = x + ((size_t)(bz * CDIM + c0 + rr)) * SEQ + s0;
#pragma unroll
    for (int i = 0; i < 4; i++){
      const int cc = q4 + i * 4;
      float4 f = *(const float4*)(src + cc * 4);
      ldsT[(cc * 4 + 0) * 72 + rr] = f2bf(f.x);
      ldsT[(cc * 4 + 1) * 72 + rr] = f2bf(f.y);
      ldsT[(cc * 4 + 2) * 72 + rr] = f2bf(f.z);
      ldsT[(cc * 4 + 3) * 72 + rr] = f2bf(f.w);
    }
    __syncthreads();
    u16* dst = xT + ((size_t)(bz * SEQ + s0 + rr)) * CDIM + c0 + q4 * 16;
    *(ushort8*)(dst)     = *(const ushort8*)&ldsT[rr * 72 + q4 * 16];
    *(ushort8*)(dst + 8) = *(const ushort8*)&ldsT[rr * 72 + q4 * 16 + 8];
  } else {
    const int NWQ = 3 * CDIM * CDIM;
    const int i = ((id - 768) * 256 + t) * 4;
    const float* src = (i < NWQ) ? (wq + i) : (wp + (i - NWQ));
    float4 f = *(const float4*)src;
    uint2v v; v[0] = packbf(f.x, f.y); v[1] = packbf(f.z, f.w);
    *(uint2v*)(wdst + i) = v;
  }
}

// ---------------- Kernel 2: QKV GEMM (128x128 tile, BK=64, async swizzled staging) ----------------
__global__ __launch_bounds__(256) void qkv_kernel(const u16* __restrict__ W,
                                                  const u16* __restrict__ xT,
                                                  u16* __restrict__ qws,
                                                  u16* __restrict__ kws,
                                                  u16* __restrict__ vws){
  __shared__ u16 ldsA[128 * 64];
  __shared__ u16 ldsB[128 * 64];
  const int t = threadIdx.x;
  const int w = t >> 6, l = t & 63;
  const int quad = l >> 4, li = l & 15;
  const int wm = w >> 1, wn = w & 1;
  const int n0 = blockIdx.x * 128;
  const int m0 = blockIdx.y * 128;
  const int b  = blockIdx.z;

  floatx4 acc[4][4];
#pragma unroll
  for (int i = 0; i < 4; i++)
#pragma unroll
    for (int j = 0; j < 4; j++) acc[i][j] = (floatx4)0.0f;

  const u16* xb = xT + (size_t)b * SEQ * CDIM;
  const int swz = li & 7;

  for (int kk = 0; kk < CDIM; kk += 64){
    __syncthreads();
#pragma unroll
    for (int rep = 0; rep < 4; rep++){
      const int cs = rep * 256 + t;
      const int row = cs >> 3, c4 = cs & 7;
      const int gcol = ((c4 ^ (row & 7)) << 3);
      async16(&W [(size_t)(m0 + row) * CDIM + kk + gcol], &ldsA[cs * 8]);
      async16(&xb[(size_t)(n0 + row) * CDIM + kk + gcol], &ldsB[cs * 8]);
    }
    __syncthreads();
#pragma unroll
    for (int kc = 0; kc < 2; kc++){
      const int rc = ((kc * 4 + quad) ^ swz) << 3;
      short8 af[4], bf[4];
#pragma unroll
      for (int i = 0; i < 4; i++)
        af[i] = *(const short8*)&ldsA[(wm * 64 + i * 16 + li) * 64 + rc];
#pragma unroll
      for (int j = 0; j < 4; j++)
        bf[j] = *(const short8*)&ldsB[(wn * 64 + j * 16 + li) * 64 + rc];
#pragma unroll
      for (int i = 0; i < 4; i++)
#pragma unroll
        for (int j = 0; j < 4; j++)
          acc[i][j] = __builtin_amdgcn_mfma_f32_16x16x32_bf16(af[i], bf[j], acc[i][j], 0, 0, 0);
    }
  }

  const float qs = 0.14433756729740643f * 1.4426950408889634f; // d^-0.5 * log2(e)
  const uint2v z2 = (uint2v)0u;
#pragma unroll
  for (int i = 0; i < 4; i++){
    const int obase = m0 + wm * 64 + i * 16 + quad * 4;
    const int which = obase / CDIM;
    const int rem = obase - which * CDIM;
    const int h = rem / DH;
    const int dd = rem - h * DH;
    const int pair = b * NH + h;
#pragma unroll
    for (int j = 0; j < 4; j++){
      const int s = n0 + wn * 64 + j * 16 + li;
      floatx4 v = acc[i][j];
      if (which == 0){
        uint2v pk; pk[0] = packbf(v[0] * qs, v[1] * qs); pk[1] = packbf(v[2] * qs, v[3] * qs);
        *(uint2v*)&qws[((size_t)pair * SEQ + s) * DP + dd] = pk;
        if ((dd & 48) == 32)
          *(uint2v*)&qws[((size_t)pair * SEQ + s) * DP + dd + 16] = z2;
      } else if (which == 1){
        uint2v pk; pk[0] = packbf(v[0], v[1]); pk[1] = packbf(v[2], v[3]);
        *(uint2v*)&kws[((size_t)pair * SEQ + s) * DP + dd] = pk;
        if ((dd & 48) == 32)
          *(uint2v*)&kws[((size_t)pair * SEQ + s) * DP + dd + 16] = z2;
      } else {
#pragma unroll
        for (int r = 0; r < 4; r++)
          vws[((size_t)pair * DH + dd + r) * SEQ + s] = f2bf(v[r]);
      }
    }
  }
}

// ---------------- Kernel 3: flash attention, 16 q/wave, 4 blocks/CU ----------------
// 1-D grid of 1024: pair = id & 63, qb = id >> 6  =>  id % 8 == pair % 8 (XCD sharing)
// block = 4 waves x 16 queries = 64 q; KV tiles of 64, double-buffered prefetch.
// LDS: K 2x8KB + V 2x6KB + P 9KB = 37 KB -> 4 blocks/CU (16 waves/CU).
__global__ __launch_bounds__(256) void attn_kernel(const u16* __restrict__ qws,
                                                   const u16* __restrict__ kws,
                                                   const u16* __restrict__ vws,
                                                   u16* __restrict__ aT){
  __shared__ u16 ldsK[2][64 * 64];
  __shared__ u16 ldsV[2][48 * 64];
  __shared__ u16 ldsP[64 * 72];

  const int t = threadIdx.x;
  const int w = t >> 6, l = t & 63;
  const int quad = l >> 4, li = l & 15;
  const int id = blockIdx.x;
  const int pair = id & 63;
  const int qb = id >> 6;
  const int b = pair >> 3, h = pair & 7;
  const int qbase = qb * 64 + w * 16;
  const int swz = li & 7;

  // Q fragment (B-operand): lane li = query qbase+li, k = quad*8+j (cols 48..63 zero)
  const u16* qrow = qws + ((size_t)pair * SEQ + qbase + li) * DP;
  const short8 qf0 = *(const short8*)(qrow + quad * 8);
  const short8 qf1 = *(const short8*)(qrow + 32 + quad * 8);

  floatx4 ot[3];
#pragma unroll
  for (int dt = 0; dt < 3; dt++) ot[dt] = (floatx4)0.0f;
  float m_run = -3.0e38f, l_run = 0.0f;

  const u16* kbase = kws + (size_t)pair * SEQ * DP;
  const u16* vbase = vws + (size_t)pair * DH * SEQ;

  auto stage = [&](int kv, int pp){
#pragma unroll
    for (int rep = 0; rep < 4; rep++){
      const int cs = rep * 256 + t;
      if (cs < 512){
        const int row = cs >> 3, c4 = cs & 7;
        async16(&kbase[(size_t)(kv + row) * DP + ((c4 ^ (row & 7)) << 3)],
                &ldsK[pp][cs * 8]);
      } else if (cs < 896){
        const int cs2 = cs - 512;
        const int row = cs2 >> 3, c4 = cs2 & 7;
        async16(&vbase[(size_t)row * SEQ + kv + ((c4 ^ (row & 7)) << 3)],
                &ldsV[pp][cs2 * 8]);
      }
    }
  };

  u16* prow = ldsP + (w * 16 + li) * 72;

  stage(0, 0);
  for (int i = 0; i < 16; i++){
    const int p = i & 1;
    __syncthreads();                 // drains stage(i) (overlapped with tile i-1 compute)
    if (i < 15) stage((i + 1) * 64, p ^ 1);   // drains at NEXT loop-top barrier

    // ---- S^T[y][m] = K[y][:] . Q[m][:] ----
    floatx4 st[4];
#pragma unroll
    for (int yt = 0; yt < 4; yt++){
      const u16* krow = ldsK[p] + (yt * 16 + li) * 64;
      const short8 kf0 = *(const short8*)(krow + (((0 + quad) ^ swz) << 3));
      const short8 kf1 = *(const short8*)(krow + (((4 + quad) ^ swz) << 3));
      floatx4 z = (floatx4)0.0f;
      z = __builtin_amdgcn_mfma_f32_16x16x32_bf16(kf0, qf0, z, 0, 0, 0);
      z = __builtin_amdgcn_mfma_f32_16x16x32_bf16(kf1, qf1, z, 0, 0, 0);
      st[yt] = z;
    }

    // ---- online softmax; per-query stats (query = lane&15), cross-quad reduce ----
    float mx = -3.0e38f;
#pragma unroll
    for (int yt = 0; yt < 4; yt++)
#pragma unroll
      for (int r = 0; r < 4; r++) mx = fmaxf(mx, st[yt][r]);
    mx = fmaxf(mx, __shfl_xor(mx, 16, 64));
    mx = fmaxf(mx, __shfl_xor(mx, 32, 64));
    const float mnew = fmaxf(m_run, mx);
    const float alpha = __builtin_amdgcn_exp2f(m_run - mnew);
    m_run = mnew;

    float ls = 0.0f;
#pragma unroll
    for (int yt = 0; yt < 4; yt++){
      float p0 = __builtin_amdgcn_exp2f(st[yt][0] - mnew);
      float p1 = __builtin_amdgcn_exp2f(st[yt][1] - mnew);
      float p2 = __builtin_amdgcn_exp2f(st[yt][2] - mnew);
      float p3 = __builtin_amdgcn_exp2f(st[yt][3] - mnew);
      ls += (p0 + p1) + (p2 + p3);
      uint2v pk; pk[0] = packbf(p0, p1); pk[1] = packbf(p2, p3);
      *(uint2v*)&prow[yt * 16 + quad * 4] = pk;
    }
    l_run = l_run * alpha + ls;
#pragma unroll
    for (int dt = 0; dt < 3; dt++) ot[dt] *= alpha;
    // no barrier: each wave reads only its own P rows (lgkmcnt orders write->read)

    // ---- O^T[d][m] += Vt[d][y] . P[y][m] ----
#pragma unroll
    for (int ks = 0; ks < 64; ks += 32){
      const short8 pb = *(const short8*)&ldsP[(w * 16 + li) * 72 + ks + quad * 8];
#pragma unroll
      for (int dt = 0; dt < 3; dt++){
        const short8 vf = *(const short8*)&ldsV[p][(dt * 16 + li) * 64 +
                                                  ((((ks >> 3) + quad) ^ swz) << 3)];
        ot[dt] = __builtin_amdgcn_mfma_f32_16x16x32_bf16(vf, pb, ot[dt], 0, 0, 0);
      }
    }
  }

  // cross-quad l reduction and write-out
  float ls = l_run;
  ls += __shfl_xor(ls, 16, 64);
  ls += __shfl_xor(ls, 32, 64);
  const float rl = __builtin_amdgcn_rcpf(ls);
  const int q = qbase + li;
#pragma unroll
  for (int dt = 0; dt < 3; dt++){
    floatx4 v = ot[dt];
    uint2v pk; pk[0] = packbf(v[0] * rl, v[1] * rl); pk[1] = packbf(v[2] * rl, v[3] * rl);
    *(uint2v*)&aT[((size_t)b * SEQ + q) * CDIM + h * DH + dt * 16 + quad * 4] = pk;
  }
}

// ---------------- Kernel 4: proj GEMM (128x128 tile, BK=64, async), fp32 out + bias ----------------
__global__ __launch_bounds__(256) void proj_kernel(const u16* __restrict__ W,
                                                   const u16* __restrict__ aT,
                                                   const float* __restrict__ bias,
                                                   float* __restrict__ out){
  __shared__ u16 ldsA[128 * 64];
  __shared__ u16 ldsB[128 * 64];
  const int t = threadIdx.x;
  const int w = t >> 6, l = t & 63;
  const int quad = l >> 4, li = l & 15;
  const int wm = w >> 1, wn = w & 1;
  const int n0 = blockIdx.x * 128;
  const int m0 = blockIdx.y * 128;
  const int b  = blockIdx.z;

  floatx4 acc[4][4];
#pragma unroll
  for (int i = 0; i < 4; i++)
#pragma unroll
    for (int j = 0; j < 4; j++) acc[i][j] = (floatx4)0.0f;

  const u16* ab = aT + (size_t)b * SEQ * CDIM;
  const int swz = li & 7;

  for (int kk = 0; kk < CDIM; kk += 64){
    __syncthreads();
#pragma unroll
    for (int rep = 0; rep < 4; rep++){
      const int cs = rep * 256 + t;
      const int row = cs >> 3, c4 = cs & 7;
      const int gcol = ((c4 ^ (row & 7)) << 3);
      async16(&W [(size_t)(m0 + row) * CDIM + kk + gcol], &ldsA[cs * 8]);
      async16(&ab[(size_t)(n0 + row) * CDIM + kk + gcol], &ldsB[cs * 8]);
    }
    __syncthreads();
#pragma unroll
    for (int kc = 0; kc < 2; kc++){
      const int rc = ((kc * 4 + quad) ^ swz) << 3;
      short8 af[4], bf[4];
#pragma unroll
      for (int i = 0; i < 4; i++)
        af[i] = *(const short8*)&ldsA[(wm * 64 + i * 16 + li) * 64 + rc];
#pragma unroll
      for (int j = 0; j < 4; j++)
        bf[j] = *(const short8*)&ldsB[(wn * 64 + j * 16 + li) * 64 + rc];
#pragma unroll
      for (int i = 0; i < 4; i++)
#pragma unroll
        for (int j = 0; j < 4; j++)
          acc[i][j] = __builtin_amdgcn_mfma_f32_16x16x32_bf16(af[i], bf[j], acc[i][j], 0, 0, 0);
    }
  }

#pragma unroll
  for (int i = 0; i < 4; i++){
    const int o0 = m0 + wm * 64 + i * 16 + quad * 4;
    float bs[4];
#pragma unroll
    for (int r = 0; r < 4; r++) bs[r] = bias[o0 + r];
#pragma unroll
    for (int j = 0; j < 4; j++){
      const int s = n0 + wn * 64 + j * 16 + li;
#pragma unroll
      for (int r = 0; r < 4; r++)
        out[((size_t)b * CDIM + o0 + r) * SEQ + s] = acc[i][j][r] + bs[r];
    }
  }
}

extern "C" void kernel_launch(void* const* d_in, const int* in_sizes, int n_in,
                              void* d_out, int out_size, void* d_ws, size_t ws_size,
                              hipStream_t stream) {
  const float* x      = (const float*)d_in[0];
  const float* w_qkv  = (const float*)d_in[1];
  const float* w_proj = (const float*)d_in[2];
  const float* b_proj = (const float*)d_in[3];
  float* out = (float*)d_out;

  char* ws = (char*)d_ws;
  const size_t SZX = (size_t)NB * SEQ * CDIM * sizeof(u16);       // 6 MB (xT / aT)
  const size_t SZQ = (size_t)NB * NH * SEQ * DP * sizeof(u16);    // 8 MB (padded Q/K)
  const size_t SZV = (size_t)NB * NH * SEQ * DH * sizeof(u16);    // 6 MB
  u16* xT   = (u16*)(ws);
  u16* qws  = (u16*)(ws + SZX);
  u16* kws  = (u16*)(ws + SZX + SZQ);
  u16* vws  = (u16*)(ws + SZX + 2 * SZQ);
  u16* wq_b = (u16*)(ws + SZX + 2 * SZQ + SZV);
  u16* wp_b = wq_b + (size_t)3 * CDIM * CDIM;
  u16* aT   = xT;

  prep_kernel<<<dim3(768 + 576), 256, 0, stream>>>(x, w_qkv, w_proj, xT, wq_b);
  qkv_kernel<<<dim3(8, 9, 8), 256, 0, stream>>>(wq_b, xT, qws, kws, vws);
  attn_kernel<<<dim3(1024), 256, 0, stream>>>(qws, kws, vws, aT);
  proj_kernel<<<dim3(8, 3, 8), 256, 0, stream>>>(wp_b, aT, b_proj, out);
}

// Round 12
// 127.023 us; speedup vs baseline: 1.0828x; 1.0643x over previous
//
#include <hip/hip_runtime.h>
#include <math.h>

typedef unsigned short u16;
typedef __attribute__((ext_vector_type(8))) short short8;
typedef __attribute__((ext_vector_type(8))) unsigned short ushort8;
typedef __attribute__((ext_vector_type(4))) float floatx4;
typedef __attribute__((ext_vector_type(2))) unsigned int uint2v;

#define SEQ 1024
#define CDIM 384
#define NH 8
#define DH 48
#define DP 64   // padded head dim for Q/K storage
#define NB 8

__device__ __forceinline__ u16 f2bf(float f){
  unsigned int u; __builtin_memcpy(&u, &f, 4);
  u = (u + 0x7fffu + ((u >> 16) & 1u)) >> 16;
  return (u16)u;
}
// pack two fp32 -> two bf16 (RTNE) in one u32: low16 = a, high16 = b
__device__ __forceinline__ unsigned packbf(float a, float b){
  unsigned ua, ub; __builtin_memcpy(&ua, &a, 4); __builtin_memcpy(&ub, &b, 4);
  ua += 0x7fffu + ((ua >> 16) & 1u);
  ub += 0x7fffu + ((ub >> 16) & 1u);
  return __builtin_amdgcn_perm(ub, ua, 0x07060302);
}
__device__ __forceinline__ void async16(const u16* g, u16* l){
  __builtin_amdgcn_global_load_lds((const __attribute__((address_space(1))) void*)g,
                                   (__attribute__((address_space(3))) void*)l, 16, 0, 0);
}

// ---------------- Kernel 1: fused prep ----------------
__global__ __launch_bounds__(256) void prep_kernel(const float* __restrict__ x,
                                                   const float* __restrict__ wq,
                                                   const float* __restrict__ wp,
                                                   u16* __restrict__ xT,
                                                   u16* __restrict__ wdst){
  __shared__ u16 ldsT[64 * 72];
  const int id = blockIdx.x;
  const int t = threadIdx.x;
  if (id < 768){
    const int bx = id & 15, by = (id >> 4) % 6, bz = id / 96;
    const int c0 = by * 64;
    const int s0 = bx * 64;
    const int rr = t >> 2, q4 = t & 3;

    const float* src = x + ((size_t)(bz * CDIM + c0 + rr)) * SEQ + s0;
#pragma unroll
    for (int i = 0; i < 4; i++){
      const int cc = q4 + i * 4;
      float4 f = *(const float4*)(src + cc * 4);
      ldsT[(cc * 4 + 0) * 72 + rr] = f2bf(f.x);
      ldsT[(cc * 4 + 1) * 72 + rr] = f2bf(f.y);
      ldsT[(cc * 4 + 2) * 72 + rr] = f2bf(f.z);
      ldsT[(cc * 4 + 3) * 72 + rr] = f2bf(f.w);
    }
    __syncthreads();
    u16* dst = xT + ((size_t)(bz * SEQ + s0 + rr)) * CDIM + c0 + q4 * 16;
    *(ushort8*)(dst)     = *(const ushort8*)&ldsT[rr * 72 + q4 * 16];
    *(ushort8*)(dst + 8) = *(const ushort8*)&ldsT[rr * 72 + q4 * 16 + 8];
  } else {
    const int NWQ = 3 * CDIM * CDIM;
    const int i = ((id - 768) * 256 + t) * 4;
    const float* src = (i < NWQ) ? (wq + i) : (wp + (i - NWQ));
    float4 f = *(const float4*)src;
    uint2v v; v[0] = packbf(f.x, f.y); v[1] = packbf(f.z, f.w);
    *(uint2v*)(wdst + i) = v;
  }
}

// ---------------- Kernel 2: QKV GEMM (128x64 tile, BK=64, async swizzled staging) ----------------
// grid (16, 9, 8) = 1152 blocks
__global__ __launch_bounds__(256) void qkv_kernel(const u16* __restrict__ W,
                                                  const u16* __restrict__ xT,
                                                  u16* __restrict__ qws,
                                                  u16* __restrict__ kws,
                                                  u16* __restrict__ vws){
  __shared__ u16 ldsA[128 * 64];
  __shared__ u16 ldsB[64 * 64];
  const int t = threadIdx.x;
  const int w = t >> 6, l = t & 63;
  const int quad = l >> 4, li = l & 15;
  const int n0 = blockIdx.x * 64;
  const int m0 = blockIdx.y * 128;
  const int b  = blockIdx.z;

  floatx4 acc[2][4];
#pragma unroll
  for (int i = 0; i < 2; i++)
#pragma unroll
    for (int j = 0; j < 4; j++) acc[i][j] = (floatx4)0.0f;

  const u16* xb = xT + (size_t)b * SEQ * CDIM;
  const int swz = li & 7;

  for (int kk = 0; kk < CDIM; kk += 64){
    __syncthreads();
#pragma unroll
    for (int rep = 0; rep < 4; rep++){           // A: 1024 chunks
      const int cs = rep * 256 + t;
      const int row = cs >> 3, c4 = cs & 7;
      async16(&W[(size_t)(m0 + row) * CDIM + kk + ((c4 ^ (row & 7)) << 3)], &ldsA[cs * 8]);
    }
#pragma unroll
    for (int rep = 0; rep < 2; rep++){           // B: 512 chunks
      const int cs = rep * 256 + t;
      const int row = cs >> 3, c4 = cs & 7;
      async16(&xb[(size_t)(n0 + row) * CDIM + kk + ((c4 ^ (row & 7)) << 3)], &ldsB[cs * 8]);
    }
    __syncthreads();
#pragma unroll
    for (int kc = 0; kc < 2; kc++){
      const int rc = ((kc * 4 + quad) ^ swz) << 3;
      short8 af[2], bf[4];
#pragma unroll
      for (int i = 0; i < 2; i++)
        af[i] = *(const short8*)&ldsA[(w * 32 + i * 16 + li) * 64 + rc];
#pragma unroll
      for (int j = 0; j < 4; j++)
        bf[j] = *(const short8*)&ldsB[(j * 16 + li) * 64 + rc];
#pragma unroll
      for (int i = 0; i < 2; i++)
#pragma unroll
        for (int j = 0; j < 4; j++)
          acc[i][j] = __builtin_amdgcn_mfma_f32_16x16x32_bf16(af[i], bf[j], acc[i][j], 0, 0, 0);
    }
  }

  const float qs = 0.14433756729740643f * 1.4426950408889634f; // d^-0.5 * log2(e)
  const uint2v z2 = (uint2v)0u;
#pragma unroll
  for (int i = 0; i < 2; i++){
    const int obase = m0 + w * 32 + i * 16 + quad * 4;
    const int which = obase / CDIM;
    const int rem = obase - which * CDIM;
    const int h = rem / DH;
    const int dd = rem - h * DH;
    const int pair = b * NH + h;
#pragma unroll
    for (int j = 0; j < 4; j++){
      const int s = n0 + j * 16 + li;
      floatx4 v = acc[i][j];
      if (which == 0){
        uint2v pk; pk[0] = packbf(v[0] * qs, v[1] * qs); pk[1] = packbf(v[2] * qs, v[3] * qs);
        *(uint2v*)&qws[((size_t)pair * SEQ + s) * DP + dd] = pk;
        if ((dd & 48) == 32)
          *(uint2v*)&qws[((size_t)pair * SEQ + s) * DP + dd + 16] = z2;
      } else if (which == 1){
        uint2v pk; pk[0] = packbf(v[0], v[1]); pk[1] = packbf(v[2], v[3]);
        *(uint2v*)&kws[((size_t)pair * SEQ + s) * DP + dd] = pk;
        if ((dd & 48) == 32)
          *(uint2v*)&kws[((size_t)pair * SEQ + s) * DP + dd + 16] = z2;
      } else {
#pragma unroll
        for (int r = 0; r < 4; r++)
          vws[((size_t)pair * DH + dd + r) * SEQ + s] = f2bf(v[r]);
      }
    }
  }
}

// ---------------- Kernel 3: flash attention, 16 q/wave, 4 blocks/CU ----------------
// 1-D grid of 1024: pair = id & 63, qb = id >> 6  =>  id % 8 == pair % 8 (XCD sharing)
__global__ __launch_bounds__(256) void attn_kernel(const u16* __restrict__ qws,
                                                   const u16* __restrict__ kws,
                                                   const u16* __restrict__ vws,
                                                   u16* __restrict__ aT){
  __shared__ u16 ldsK[2][64 * 64];
  __shared__ u16 ldsV[2][48 * 64];
  __shared__ u16 ldsP[64 * 72];

  const int t = threadIdx.x;
  const int w = t >> 6, l = t & 63;
  const int quad = l >> 4, li = l & 15;
  const int id = blockIdx.x;
  const int pair = id & 63;
  const int qb = id >> 6;
  const int b = pair >> 3, h = pair & 7;
  const int qbase = qb * 64 + w * 16;
  const int swz = li & 7;

  const u16* qrow = qws + ((size_t)pair * SEQ + qbase + li) * DP;
  const short8 qf0 = *(const short8*)(qrow + quad * 8);
  const short8 qf1 = *(const short8*)(qrow + 32 + quad * 8);

  floatx4 ot[3];
#pragma unroll
  for (int dt = 0; dt < 3; dt++) ot[dt] = (floatx4)0.0f;
  float m_run = -3.0e38f, l_run = 0.0f;

  const u16* kbase = kws + (size_t)pair * SEQ * DP;
  const u16* vbase = vws + (size_t)pair * DH * SEQ;

  auto stage = [&](int kv, int pp){
#pragma unroll
    for (int rep = 0; rep < 4; rep++){
      const int cs = rep * 256 + t;
      if (cs < 512){
        const int row = cs >> 3, c4 = cs & 7;
        async16(&kbase[(size_t)(kv + row) * DP + ((c4 ^ (row & 7)) << 3)],
                &ldsK[pp][cs * 8]);
      } else if (cs < 896){
        const int cs2 = cs - 512;
        const int row = cs2 >> 3, c4 = cs2 & 7;
        async16(&vbase[(size_t)row * SEQ + kv + ((c4 ^ (row & 7)) << 3)],
                &ldsV[pp][cs2 * 8]);
      }
    }
  };

  u16* prow = ldsP + (w * 16 + li) * 72;

  stage(0, 0);
  for (int i = 0; i < 16; i++){
    const int p = i & 1;
    __syncthreads();
    if (i < 15) stage((i + 1) * 64, p ^ 1);

    floatx4 st[4];
#pragma unroll
    for (int yt = 0; yt < 4; yt++){
      const u16* krow = ldsK[p] + (yt * 16 + li) * 64;
      const short8 kf0 = *(const short8*)(krow + (((0 + quad) ^ swz) << 3));
      const short8 kf1 = *(const short8*)(krow + (((4 + quad) ^ swz) << 3));
      floatx4 z = (floatx4)0.0f;
      z = __builtin_amdgcn_mfma_f32_16x16x32_bf16(kf0, qf0, z, 0, 0, 0);
      z = __builtin_amdgcn_mfma_f32_16x16x32_bf16(kf1, qf1, z, 0, 0, 0);
      st[yt] = z;
    }

    float mx = -3.0e38f;
#pragma unroll
    for (int yt = 0; yt < 4; yt++)
#pragma unroll
      for (int r = 0; r < 4; r++) mx = fmaxf(mx, st[yt][r]);
    mx = fmaxf(mx, __shfl_xor(mx, 16, 64));
    mx = fmaxf(mx, __shfl_xor(mx, 32, 64));
    const float mnew = fmaxf(m_run, mx);
    const float alpha = __builtin_amdgcn_exp2f(m_run - mnew);
    m_run = mnew;

    float ls = 0.0f;
#pragma unroll
    for (int yt = 0; yt < 4; yt++){
      float p0 = __builtin_amdgcn_exp2f(st[yt][0] - mnew);
      float p1 = __builtin_amdgcn_exp2f(st[yt][1] - mnew);
      float p2 = __builtin_amdgcn_exp2f(st[yt][2] - mnew);
      float p3 = __builtin_amdgcn_exp2f(st[yt][3] - mnew);
      ls += (p0 + p1) + (p2 + p3);
      uint2v pk; pk[0] = packbf(p0, p1); pk[1] = packbf(p2, p3);
      *(uint2v*)&prow[yt * 16 + quad * 4] = pk;
    }
    l_run = l_run * alpha + ls;
#pragma unroll
    for (int dt = 0; dt < 3; dt++) ot[dt] *= alpha;

#pragma unroll
    for (int ks = 0; ks < 64; ks += 32){
      const short8 pb = *(const short8*)&ldsP[(w * 16 + li) * 72 + ks + quad * 8];
#pragma unroll
      for (int dt = 0; dt < 3; dt++){
        const short8 vf = *(const short8*)&ldsV[p][(dt * 16 + li) * 64 +
                                                  ((((ks >> 3) + quad) ^ swz) << 3)];
        ot[dt] = __builtin_amdgcn_mfma_f32_16x16x32_bf16(vf, pb, ot[dt], 0, 0, 0);
      }
    }
  }

  float ls = l_run;
  ls += __shfl_xor(ls, 16, 64);
  ls += __shfl_xor(ls, 32, 64);
  const float rl = __builtin_amdgcn_rcpf(ls);
  const int q = qbase + li;
#pragma unroll
  for (int dt = 0; dt < 3; dt++){
    floatx4 v = ot[dt];
    uint2v pk; pk[0] = packbf(v[0] * rl, v[1] * rl); pk[1] = packbf(v[2] * rl, v[3] * rl);
    *(uint2v*)&aT[((size_t)b * SEQ + q) * CDIM + h * DH + dt * 16 + quad * 4] = pk;
  }
}

// ---------------- Kernel 4: proj GEMM (128x64 tile, BK=64, async), fp32 out + bias ----------------
// grid (16, 3, 8) = 384 blocks
__global__ __launch_bounds__(256) void proj_kernel(const u16* __restrict__ W,
                                                   const u16* __restrict__ aT,
                                                   const float* __restrict__ bias,
                                                   float* __restrict__ out){
  __shared__ u16 ldsA[128 * 64];
  __shared__ u16 ldsB[64 * 64];
  const int t = threadIdx.x;
  const int w = t >> 6, l = t & 63;
  const int quad = l >> 4, li = l & 15;
  const int n0 = blockIdx.x * 64;
  const int m0 = blockIdx.y * 128;
  const int b  = blockIdx.z;

  floatx4 acc[2][4];
#pragma unroll
  for (int i = 0; i < 2; i++)
#pragma unroll
    for (int j = 0; j < 4; j++) acc[i][j] = (floatx4)0.0f;

  const u16* ab = aT + (size_t)b * SEQ * CDIM;
  const int swz = li & 7;

  for (int kk = 0; kk < CDIM; kk += 64){
    __syncthreads();
#pragma unroll
    for (int rep = 0; rep < 4; rep++){
      const int cs = rep * 256 + t;
      const int row = cs >> 3, c4 = cs & 7;
      async16(&W[(size_t)(m0 + row) * CDIM + kk + ((c4 ^ (row & 7)) << 3)], &ldsA[cs * 8]);
    }
#pragma unroll
    for (int rep = 0; rep < 2; rep++){
      const int cs = rep * 256 + t;
      const int row = cs >> 3, c4 = cs & 7;
      async16(&ab[(size_t)(n0 + row) * CDIM + kk + ((c4 ^ (row & 7)) << 3)], &ldsB[cs * 8]);
    }
    __syncthreads();
#pragma unroll
    for (int kc = 0; kc < 2; kc++){
      const int rc = ((kc * 4 + quad) ^ swz) << 3;
      short8 af[2], bf[4];
#pragma unroll
      for (int i = 0; i < 2; i++)
        af[i] = *(const short8*)&ldsA[(w * 32 + i * 16 + li) * 64 + rc];
#pragma unroll
      for (int j = 0; j < 4; j++)
        bf[j] = *(const short8*)&ldsB[(j * 16 + li) * 64 + rc];
#pragma unroll
      for (int i = 0; i < 2; i++)
#pragma unroll
        for (int j = 0; j < 4; j++)
          acc[i][j] = __builtin_amdgcn_mfma_f32_16x16x32_bf16(af[i], bf[j], acc[i][j], 0, 0, 0);
    }
  }

#pragma unroll
  for (int i = 0; i < 2; i++){
    const int o0 = m0 + w * 32 + i * 16 + quad * 4;
    float bs[4];
#pragma unroll
    for (int r = 0; r < 4; r++) bs[r] = bias[o0 + r];
#pragma unroll
    for (int j = 0; j < 4; j++){
      const int s = n0 + j * 16 + li;
#pragma unroll
      for (int r = 0; r < 4; r++)
        out[((size_t)b * CDIM + o0 + r) * SEQ + s] = acc[i][j][r] + bs[r];
    }
  }
}

extern "C" void kernel_launch(void* const* d_in, const int* in_sizes, int n_in,
                              void* d_out, int out_size, void* d_ws, size_t ws_size,
                              hipStream_t stream) {
  const float* x      = (const float*)d_in[0];
  const float* w_qkv  = (const float*)d_in[1];
  const float* w_proj = (const float*)d_in[2];
  const float* b_proj = (const float*)d_in[3];
  float* out = (float*)d_out;

  char* ws = (char*)d_ws;
  const size_t SZX = (size_t)NB * SEQ * CDIM * sizeof(u16);       // 6 MB (xT / aT)
  const size_t SZQ = (size_t)NB * NH * SEQ * DP * sizeof(u16);    // 8 MB (padded Q/K)
  const size_t SZV = (size_t)NB * NH * SEQ * DH * sizeof(u16);    // 6 MB
  u16* xT   = (u16*)(ws);
  u16* qws  = (u16*)(ws + SZX);
  u16* kws  = (u16*)(ws + SZX + SZQ);
  u16* vws  = (u16*)(ws + SZX + 2 * SZQ);
  u16* wq_b = (u16*)(ws + SZX + 2 * SZQ + SZV);
  u16* wp_b = wq_b + (size_t)3 * CDIM * CDIM;
  u16* aT   = xT;

  prep_kernel<<<dim3(768 + 576), 256, 0, stream>>>(x, w_qkv, w_proj, xT, wq_b);
  qkv_kernel<<<dim3(16, 9, 8), 256, 0, stream>>>(wq_b, xT, qws, kws, vws);
  attn_kernel<<<dim3(1024), 256, 0, stream>>>(qws, kws, vws, aT);
  proj_kernel<<<dim3(16, 3, 8), 256, 0, stream>>>(wp_b, aT, b_proj, out);
}